// Round 17
// baseline (107.789 us; speedup 1.0000x reference)
//
#include <hip/hip_runtime.h>
#include <math.h>

#define ROWLEN 2048
#define NTHREADS 256

typedef float f32x4 __attribute__((ext_vector_type(4)));

// One block per row, 8 consecutive elements per thread. Reference semantics
// (verified r13-r15): XLA:CPU fast-math = arcp reciprocal-muls (x*(1/s),
// xi*(1/x0i), deq*(1/dsum)), PLAIN subtract, no FMA in r/z, exp2 via
// Eigen/Cephes expf(k*ln2f) table, true f32 divide for R.
// esum bracketing = r15's exactly (per-thread 8-seq fold -> 64-lane
// butterfly -> (s0+s1)+(s2+s3)); r16 proved other orders can flip fatal
// elements, so this is pinned.
// Perf vs r15 (bit-identical compute): bump's two table reads fused into one
// ds_read_b64 via a pair table; nontemporal global loads/stores (streaming).
__global__ __launch_bounds__(NTHREADS) void qis_kernel(
    const float* __restrict__ x, const float* __restrict__ scale,
    float* __restrict__ out) {
  const int row = blockIdx.x;
  const long long base = (long long)row * ROWLEN;
  const int t = threadIdx.x;
  const int wave = t >> 6;

  __shared__ float  smax[4];
  __shared__ float  ssum[4];
  __shared__ float  sdq[4];
  __shared__ float  e2t[62];   // e2t[i] = eigen_exp2(i-15), k in [-15, 46]
  __shared__ float2 e2p[61];   // e2p[i] = {e2t[i], e2t[i+1]} (bump pair)

  if (t < 62) {  // Eigen pexp(k*ln2f), bit-exact emulation via f64
    const int k = t - 15;
    const double kd = (double)k;
    const double LN2F = 0.693147182464599609375;  // (double)(float)ln2
    const double C1   = 0.693359375;              // cephes C1 (11-bit)
    const double C2m  = (double)2.12194440e-4f;   // |C2|, C2 < 0
    const float  a  = (float)(kd * LN2F);     // RN32(k*ln2f) = exp arg
    const double f1 = (double)a - kd * C1;    // exact (Sterbenz)
    const float  r  = (float)(f1 + kd * C2m); // pnmadd: one RN32
    const double rd = (double)r;
    const float  p  = (float)(1.0 + (rd + 0.5 * rd * rd));  // RN32(1+r+..)
    const float  v  = (float)ldexp((double)p, k);  // exact pow2 scale
    e2t[t] = v;
    // neighbor value via wave-synchronous shuffle (all 62 lanes in wave 0)
    float vn = __shfl_down(v, 1, 64);
    if (t < 61) e2p[t] = make_float2(v, vn);  // {e2t[t], e2t[t+1]}
  }

  const float s    = scale[0];
  const float rs   = __fdiv_rn(1.0f, s);                        // 20.0f
  const float x0i  = floorf(__fmul_rn(-0.6931f, rs));           // -14
  const float bint = floorf(__fmul_rn((float)(0.96963238 / 0.35815147), rs));
  const float ss   = __fmul_rn(s, s);
  const float rss  = __fdiv_rn(1.0f, ss);
  const float cint = floorf(__fmul_rn((float)(1.0 / 0.35815147), rss));
  const float lo   = __fmul_rn(30.0f, x0i);                     // -420
  const float rx0  = __fdiv_rn(1.0f, x0i);                      // RN(-1/14)

  f32x4 va = __builtin_nontemporal_load((const f32x4*)(x + base + 8 * t));
  f32x4 vb = __builtin_nontemporal_load((const f32x4*)(x + base + 8 * t + 4));
  float xs[8];
  xs[0] = __fmul_rn(va.x, rs); xs[1] = __fmul_rn(va.y, rs);
  xs[2] = __fmul_rn(va.z, rs); xs[3] = __fmul_rn(va.w, rs);
  xs[4] = __fmul_rn(vb.x, rs); xs[5] = __fmul_rn(vb.y, rs);
  xs[6] = __fmul_rn(vb.z, rs); xs[7] = __fmul_rn(vb.w, rs);

  // ---- row max (exact, order-free) ----
  float m = xs[0];
#pragma unroll
  for (int j = 1; j < 8; j++) m = fmaxf(m, xs[j]);
#pragma unroll
  for (int o = 32; o > 0; o >>= 1) m = fmaxf(m, __shfl_xor(m, o, 64));
  if ((t & 63) == 0) smax[wave] = m;
  __syncthreads();  // barrier 1: publishes smax, e2t, e2p
  m = fmaxf(fmaxf(smax[0], smax[1]), fmaxf(smax[2], smax[3]));

  // ---- exp_int: plain sub, arcp q, no FMA, cephes exp2 scale ----
  float ei[8];
  float pe = 0.0f;
#pragma unroll
  for (int j = 0; j < 8; j++) {
    float xi = __fsub_rn(xs[j], m);                 // 0 at argmax
    xi = fmaxf(xi, lo);
    float qf = floorf(__fmul_rn(xi, rx0));          // 0..30
    float r  = __fsub_rn(xi, __fmul_rn(x0i, qf));   // no FMA
    float z  = __fadd_rn(__fmul_rn(r, __fadd_rn(r, bint)), cint);
    int   qi = (int)qf;
    float e  = floorf(__fmul_rn(z, e2t[45 - qi]));  // cephes exp2(30-q)
    ei[j] = fmaxf(e, 0.0f);
    pe = __fadd_rn(pe, ei[j]);                      // r15 bracketing (pinned)
  }
#pragma unroll
  for (int o = 32; o > 0; o >>= 1)
    pe = __fadd_rn(pe, __shfl_xor(pe, o, 64));
  if ((t & 63) == 0) ssum[wave] = pe;
  __syncthreads();  // barrier 2: ssum ready
  const float esum = __fadd_rn(__fadd_rn(ssum[0], ssum[1]),
                               __fadd_rn(ssum[2], ssum[3]));

  // ---- qlog (cephes pair-table bump) + cephes deq; butterfly dsum ----
  float dq[8];
  float pd = 0.0f;
#pragma unroll
  for (int j = 0; j < 8; j++) {
    float R = __fdiv_rn(esum, ei[j]);  // true elementwise divide
    float v = rintf(R);                // half-to-even
    unsigned ui = __float_as_uint(v);
    int big = (int)(ui >> 23) - 127;   // v >= 1
    if (big > 46) big = 46;
    float2 pr = e2p[big + 14];         // {e2t[big+14], e2t[big+15]}: one b64
    int bump = (__fsub_rn(v, pr.y) >= pr.x) ? 1 : 0;
    int q = big + bump;
    if (q > 15) q = 15;
    dq[j] = e2t[15 - q];               // cephes exp2(-q), non-dyadic
    pd += dq[j];
  }
#pragma unroll
  for (int o = 32; o > 0; o >>= 1) pd += __shfl_xor(pd, o, 64);
  if ((t & 63) == 0) sdq[wave] = pd;
  __syncthreads();  // barrier 3: sdq ready
  const float dsum = (sdq[0] + sdq[1]) + (sdq[2] + sdq[3]);
  const float dinv = __fdiv_rn(1.0f, dsum);  // arcp: deq * RN(1/dsum)

  f32x4 w0, w1;
  w0.x = __fmul_rn(dq[0], dinv); w0.y = __fmul_rn(dq[1], dinv);
  w0.z = __fmul_rn(dq[2], dinv); w0.w = __fmul_rn(dq[3], dinv);
  w1.x = __fmul_rn(dq[4], dinv); w1.y = __fmul_rn(dq[5], dinv);
  w1.z = __fmul_rn(dq[6], dinv); w1.w = __fmul_rn(dq[7], dinv);
  __builtin_nontemporal_store(w0, (f32x4*)(out + base + 8 * t));
  __builtin_nontemporal_store(w1, (f32x4*)(out + base + 8 * t + 4));
}

extern "C" void kernel_launch(void* const* d_in, const int* in_sizes, int n_in,
                              void* d_out, int out_size, void* d_ws, size_t ws_size,
                              hipStream_t stream) {
  const float* x = (const float*)d_in[0];
  const float* scale = (const float*)d_in[1];
  float* out = (float*)d_out;
  const int rows = out_size / ROWLEN;  // 32768
  qis_kernel<<<dim3(rows), dim3(NTHREADS), 0, stream>>>(x, scale, out);
}

// Round 19
// 106.931 us; speedup vs baseline: 1.0080x; 1.0080x over previous
//
#include <hip/hip_runtime.h>
#include <math.h>

#define ROWLEN 2048
#define NTHREADS 256

// 4 rows per 256-thread block; per-row computation is a VERBATIM replay of
// r15 (the 103.7us PASS): thread t folds row_k[8t..8t+8), per-wave butterfly,
// LDS (s0+s1)+(s2+s3) combine, 3 barriers -- now amortized over 4 rows.
// Reference semantics (verified r13-r15): XLA:CPU fast-math = arcp
// reciprocal-muls, PLAIN subtract, no FMA in r/z, Cephes exp2 table,
// true f32 divide for R. r16/r18 showed restructured reductions flip fatal
// elements, so the r15 dataflow is pinned exactly.
__global__ __launch_bounds__(NTHREADS) void qis_kernel(
    const float* __restrict__ x, const float* __restrict__ scale,
    float* __restrict__ out) {
  const int t = threadIdx.x;
  const int wave = t >> 6;

  __shared__ float smax[4][4];
  __shared__ float ssum[4][4];
  __shared__ float sdq[4][4];
  __shared__ float e2t[62];  // e2t[i] = eigen_exp2(i-15), k in [-15, 46]

  if (t < 62) {  // Eigen pexp(k*ln2f), bit-exact emulation via f64
    const int k = t - 15;
    const double kd = (double)k;
    const double LN2F = 0.693147182464599609375;  // (double)(float)ln2
    const double C1   = 0.693359375;              // cephes C1 (11-bit)
    const double C2m  = (double)2.12194440e-4f;   // |C2|, C2 < 0
    const float  a  = (float)(kd * LN2F);     // RN32(k*ln2f) = exp arg
    const double f1 = (double)a - kd * C1;    // exact (Sterbenz)
    const float  r  = (float)(f1 + kd * C2m); // pnmadd: one RN32
    const double rd = (double)r;
    const float  p  = (float)(1.0 + (rd + 0.5 * rd * rd));  // RN32(1+r+..)
    e2t[t] = (float)ldexp((double)p, k);      // exact pow2 scale
  }

  const float s    = scale[0];
  const float rs   = __fdiv_rn(1.0f, s);                        // 20.0f
  const float x0i  = floorf(__fmul_rn(-0.6931f, rs));           // -14
  const float bint = floorf(__fmul_rn((float)(0.96963238 / 0.35815147), rs));
  const float ss   = __fmul_rn(s, s);
  const float rss  = __fdiv_rn(1.0f, ss);
  const float cint = floorf(__fmul_rn((float)(1.0 / 0.35815147), rss));
  const float lo   = __fmul_rn(30.0f, x0i);                     // -420
  const float rx0  = __fdiv_rn(1.0f, x0i);                      // RN(-1/14)

  const long long base0 = ((long long)blockIdx.x * 4) * ROWLEN;

  // ---- load 4 rows x 8 consecutive elems/thread, arcp scale ----
  float a[4][8];
#pragma unroll
  for (int k = 0; k < 4; k++) {
    const float* p = x + base0 + (long long)k * ROWLEN + 8 * t;
    float4 va = *(const float4*)(p);
    float4 vb = *(const float4*)(p + 4);
    a[k][0] = __fmul_rn(va.x, rs); a[k][1] = __fmul_rn(va.y, rs);
    a[k][2] = __fmul_rn(va.z, rs); a[k][3] = __fmul_rn(va.w, rs);
    a[k][4] = __fmul_rn(vb.x, rs); a[k][5] = __fmul_rn(vb.y, rs);
    a[k][6] = __fmul_rn(vb.z, rs); a[k][7] = __fmul_rn(vb.w, rs);
  }

  // ---- row max per row: r15 replay (thread max, butterfly, LDS) ----
  float mk[4];
#pragma unroll
  for (int k = 0; k < 4; k++) {
    float m = a[k][0];
#pragma unroll
    for (int j = 1; j < 8; j++) m = fmaxf(m, a[k][j]);
#pragma unroll
    for (int o = 32; o > 0; o >>= 1) m = fmaxf(m, __shfl_xor(m, o, 64));
    mk[k] = m;
  }
  if ((t & 63) == 0) {
#pragma unroll
    for (int k = 0; k < 4; k++) smax[k][wave] = mk[k];
  }
  __syncthreads();  // barrier 1: smax + e2t
#pragma unroll
  for (int k = 0; k < 4; k++)
    mk[k] = fmaxf(fmaxf(smax[k][0], smax[k][1]),
                  fmaxf(smax[k][2], smax[k][3]));

  // ---- exp_int (r15 chain verbatim) + r15 esum fold/butterfly ----
  float pe[4];
#pragma unroll
  for (int k = 0; k < 4; k++) {
    pe[k] = 0.0f;
#pragma unroll
    for (int j = 0; j < 8; j++) {
      float xi = __fsub_rn(a[k][j], mk[k]);           // 0 at argmax
      xi = fmaxf(xi, lo);
      float qf = floorf(__fmul_rn(xi, rx0));          // 0..30
      float r  = __fsub_rn(xi, __fmul_rn(x0i, qf));   // no FMA
      float z  = __fadd_rn(__fmul_rn(r, __fadd_rn(r, bint)), cint);
      int   qi = (int)qf;
      float e  = floorf(__fmul_rn(z, e2t[45 - qi]));  // cephes exp2(30-q)
      e = fmaxf(e, 0.0f);
      a[k][j] = e;                                    // ei in place
      pe[k] = __fadd_rn(pe[k], e);                    // r15 thread fold
    }
#pragma unroll
    for (int o = 32; o > 0; o >>= 1)
      pe[k] = __fadd_rn(pe[k], __shfl_xor(pe[k], o, 64));
  }
  if ((t & 63) == 0) {
#pragma unroll
    for (int k = 0; k < 4; k++) ssum[k][wave] = pe[k];
  }
  __syncthreads();  // barrier 2: ssum
  float esum[4];
#pragma unroll
  for (int k = 0; k < 4; k++)
    esum[k] = __fadd_rn(__fadd_rn(ssum[k][0], ssum[k][1]),
                        __fadd_rn(ssum[k][2], ssum[k][3]));

  // ---- qlog + deq (r15 verbatim) + r15 dsum ----
  float pd[4];
#pragma unroll
  for (int k = 0; k < 4; k++) {
    pd[k] = 0.0f;
#pragma unroll
    for (int j = 0; j < 8; j++) {
      float R = __fdiv_rn(esum[k], a[k][j]);  // true elementwise divide
      float v = rintf(R);                     // half-to-even
      unsigned ui = __float_as_uint(v);
      int big = (int)(ui >> 23) - 127;        // v >= 1
      if (big > 46) big = 46;
      int bump = (__fsub_rn(v, e2t[big + 15]) >= e2t[big + 14]) ? 1 : 0;
      int q = big + bump;
      if (q > 15) q = 15;
      float d = e2t[15 - q];                  // cephes exp2(-q)
      a[k][j] = d;                            // dq in place
      pd[k] += d;                             // r15 plain-add fold
    }
#pragma unroll
    for (int o = 32; o > 0; o >>= 1)
      pd[k] += __shfl_xor(pd[k], o, 64);
  }
  if ((t & 63) == 0) {
#pragma unroll
    for (int k = 0; k < 4; k++) sdq[k][wave] = pd[k];
  }
  __syncthreads();  // barrier 3: sdq
#pragma unroll
  for (int k = 0; k < 4; k++) {
    const float dsum = (sdq[k][0] + sdq[k][1]) + (sdq[k][2] + sdq[k][3]);
    const float dinv = __fdiv_rn(1.0f, dsum);  // arcp: deq * RN(1/dsum)
    float4 w0, w1;
    w0.x = __fmul_rn(a[k][0], dinv); w0.y = __fmul_rn(a[k][1], dinv);
    w0.z = __fmul_rn(a[k][2], dinv); w0.w = __fmul_rn(a[k][3], dinv);
    w1.x = __fmul_rn(a[k][4], dinv); w1.y = __fmul_rn(a[k][5], dinv);
    w1.z = __fmul_rn(a[k][6], dinv); w1.w = __fmul_rn(a[k][7], dinv);
    float* p = out + base0 + (long long)k * ROWLEN + 8 * t;
    *(float4*)(p) = w0;
    *(float4*)(p + 4) = w1;
  }
}

extern "C" void kernel_launch(void* const* d_in, const int* in_sizes, int n_in,
                              void* d_out, int out_size, void* d_ws, size_t ws_size,
                              hipStream_t stream) {
  const float* x = (const float*)d_in[0];
  const float* scale = (const float*)d_in[1];
  float* out = (float*)d_out;
  const int rows = out_size / ROWLEN;  // 32768
  qis_kernel<<<dim3(rows / 4), dim3(NTHREADS), 0, stream>>>(x, scale, out);
}

// Round 20
// 93.157 us; speedup vs baseline: 1.1571x; 1.1479x over previous
//
#include <hip/hip_runtime.h>
#include <math.h>

#define ROWLEN 2048
#define NTHREADS 256

typedef float f32x4 __attribute__((ext_vector_type(4)));

// r15 (103.7us PASS) with two zero-numerics-risk micro-levers:
//  - nontemporal STORES only (write-once stream; loads stay cached)
//  - __launch_bounds__(256, 8): cap VGPR at 64 -> 8 waves/SIMD guaranteed
// Reference semantics (verified r13-r15/r19): XLA:CPU fast-math = arcp
// reciprocal-muls (x*(1/s), xi*(1/x0i), deq*(1/dsum)), PLAIN subtract,
// no FMA in r/z, exp2 via Eigen/Cephes expf(k*ln2f) table, true f32 divide
// for R. esum bracketing pinned to r15's exactly (r16/r18: reorders flip
// fatal elements). Compute path byte-identical to r15.
__global__ __launch_bounds__(NTHREADS, 8) void qis_kernel(
    const float* __restrict__ x, const float* __restrict__ scale,
    float* __restrict__ out) {
  const int row = blockIdx.x;
  const long long base = (long long)row * ROWLEN;
  const int t = threadIdx.x;
  const int wave = t >> 6;

  __shared__ float smax[4];
  __shared__ float ssum[4];
  __shared__ float sdq[4];
  __shared__ float e2t[62];  // e2t[i] = eigen_exp2(i-15), k in [-15, 46]

  if (t < 62) {  // Eigen pexp(k*ln2f), bit-exact emulation via f64
    const int k = t - 15;
    const double kd = (double)k;
    const double LN2F = 0.693147182464599609375;  // (double)(float)ln2
    const double C1   = 0.693359375;              // cephes C1 (11-bit)
    const double C2m  = (double)2.12194440e-4f;   // |C2|, C2 < 0
    const float  a  = (float)(kd * LN2F);     // RN32(k*ln2f) = exp arg
    const double f1 = (double)a - kd * C1;    // exact (Sterbenz)
    const float  r  = (float)(f1 + kd * C2m); // pnmadd: one RN32
    const double rd = (double)r;
    const float  p  = (float)(1.0 + (rd + 0.5 * rd * rd));  // RN32(1+r+..)
    e2t[t] = (float)ldexp((double)p, k);      // exact pow2 scale
  }

  const float s    = scale[0];
  const float rs   = __fdiv_rn(1.0f, s);                        // 20.0f
  const float x0i  = floorf(__fmul_rn(-0.6931f, rs));           // -14
  const float bint = floorf(__fmul_rn((float)(0.96963238 / 0.35815147), rs));
  const float ss   = __fmul_rn(s, s);
  const float rss  = __fdiv_rn(1.0f, ss);
  const float cint = floorf(__fmul_rn((float)(1.0 / 0.35815147), rss));
  const float lo   = __fmul_rn(30.0f, x0i);                     // -420
  const float rx0  = __fdiv_rn(1.0f, x0i);                      // RN(-1/14)

  float4 va = *(const float4*)(x + base + 8 * t);
  float4 vb = *(const float4*)(x + base + 8 * t + 4);
  float xs[8];
  {
    float xf[8] = {va.x, va.y, va.z, va.w, vb.x, vb.y, vb.z, vb.w};
#pragma unroll
    for (int j = 0; j < 8; j++) xs[j] = __fmul_rn(xf[j], rs);  // arcp
  }

  // ---- row max (exact, order-free) ----
  float m = xs[0];
#pragma unroll
  for (int j = 1; j < 8; j++) m = fmaxf(m, xs[j]);
#pragma unroll
  for (int o = 32; o > 0; o >>= 1) m = fmaxf(m, __shfl_xor(m, o, 64));
  if ((t & 63) == 0) smax[wave] = m;
  __syncthreads();  // barrier 1: publishes smax and e2t
  m = fmaxf(fmaxf(smax[0], smax[1]), fmaxf(smax[2], smax[3]));

  // ---- exp_int: plain sub, arcp q, no FMA, cephes exp2 scale ----
  float ei[8];
  float pe = 0.0f;
#pragma unroll
  for (int j = 0; j < 8; j++) {
    float xi = __fsub_rn(xs[j], m);                 // 0 at argmax
    xi = fmaxf(xi, lo);
    float qf = floorf(__fmul_rn(xi, rx0));          // 0..30
    float r  = __fsub_rn(xi, __fmul_rn(x0i, qf));   // no FMA
    float z  = __fadd_rn(__fmul_rn(r, __fadd_rn(r, bint)), cint);
    int   qi = (int)qf;
    float e  = floorf(__fmul_rn(z, e2t[45 - qi]));  // cephes exp2(30-q)
    ei[j] = fmaxf(e, 0.0f);
    pe = __fadd_rn(pe, ei[j]);                      // r15 thread fold (pinned)
  }
#pragma unroll
  for (int o = 32; o > 0; o >>= 1)
    pe = __fadd_rn(pe, __shfl_xor(pe, o, 64));
  if ((t & 63) == 0) ssum[wave] = pe;
  __syncthreads();  // barrier 2: ssum ready
  const float esum = __fadd_rn(__fadd_rn(ssum[0], ssum[1]),
                               __fadd_rn(ssum[2], ssum[3]));

  // ---- qlog (cephes-table bump) + cephes deq; butterfly dsum ----
  float dq[8];
  float pd = 0.0f;
#pragma unroll
  for (int j = 0; j < 8; j++) {
    float R = __fdiv_rn(esum, ei[j]);  // true elementwise divide
    float v = rintf(R);                // half-to-even
    unsigned ui = __float_as_uint(v);
    int big = (int)(ui >> 23) - 127;   // v >= 1
    if (big > 46) big = 46;
    int bump = (__fsub_rn(v, e2t[big + 15]) >= e2t[big + 14]) ? 1 : 0;
    int q = big + bump;
    if (q > 15) q = 15;
    dq[j] = e2t[15 - q];               // cephes exp2(-q), non-dyadic
    pd += dq[j];
  }
#pragma unroll
  for (int o = 32; o > 0; o >>= 1) pd += __shfl_xor(pd, o, 64);
  if ((t & 63) == 0) sdq[wave] = pd;
  __syncthreads();  // barrier 3: sdq ready
  const float dsum = (sdq[0] + sdq[1]) + (sdq[2] + sdq[3]);
  const float dinv = __fdiv_rn(1.0f, dsum);  // arcp: deq * RN(1/dsum)

  f32x4 w0, w1;
  w0.x = __fmul_rn(dq[0], dinv); w0.y = __fmul_rn(dq[1], dinv);
  w0.z = __fmul_rn(dq[2], dinv); w0.w = __fmul_rn(dq[3], dinv);
  w1.x = __fmul_rn(dq[4], dinv); w1.y = __fmul_rn(dq[5], dinv);
  w1.z = __fmul_rn(dq[6], dinv); w1.w = __fmul_rn(dq[7], dinv);
  __builtin_nontemporal_store(w0, (f32x4*)(out + base + 8 * t));
  __builtin_nontemporal_store(w1, (f32x4*)(out + base + 8 * t + 4));
}

extern "C" void kernel_launch(void* const* d_in, const int* in_sizes, int n_in,
                              void* d_out, int out_size, void* d_ws, size_t ws_size,
                              hipStream_t stream) {
  const float* x = (const float*)d_in[0];
  const float* scale = (const float*)d_in[1];
  float* out = (float*)d_out;
  const int rows = out_size / ROWLEN;  // 32768
  qis_kernel<<<dim3(rows), dim3(NTHREADS), 0, stream>>>(x, scale, out);
}

// Round 21
// 89.822 us; speedup vs baseline: 1.2000x; 1.0371x over previous
//
#include <hip/hip_runtime.h>
#include <math.h>

#define ROWLEN 2048
#define NTHREADS 256

typedef float f32x4 __attribute__((ext_vector_type(4)));

// 2 rows per 256-thread block; per-row computation is a VERBATIM r15 replay
// (r19 proved bit-identical output), plus r20's proven levers:
// nontemporal STORES + __launch_bounds__(256, 8). Motivation: double the
// independent float4 load streams per thread (MLP) now that occupancy and
// write-path are fixed. Reference semantics (verified r13+): XLA:CPU
// fast-math = arcp reciprocal-muls, PLAIN subtract, no FMA in r/z, Cephes
// exp2 table, true f32 divide for R; r15 esum bracketing pinned.
__global__ __launch_bounds__(NTHREADS, 8) void qis_kernel(
    const float* __restrict__ x, const float* __restrict__ scale,
    float* __restrict__ out) {
  const int t = threadIdx.x;
  const int wave = t >> 6;
  const long long base0 = ((long long)blockIdx.x * 2) * ROWLEN;

  __shared__ float smax[2][4];
  __shared__ float ssum[2][4];
  __shared__ float sdq[2][4];
  __shared__ float e2t[62];  // e2t[i] = eigen_exp2(i-15), k in [-15, 46]

  if (t < 62) {  // Eigen pexp(k*ln2f), bit-exact emulation via f64
    const int k = t - 15;
    const double kd = (double)k;
    const double LN2F = 0.693147182464599609375;  // (double)(float)ln2
    const double C1   = 0.693359375;              // cephes C1 (11-bit)
    const double C2m  = (double)2.12194440e-4f;   // |C2|, C2 < 0
    const float  a  = (float)(kd * LN2F);     // RN32(k*ln2f) = exp arg
    const double f1 = (double)a - kd * C1;    // exact (Sterbenz)
    const float  r  = (float)(f1 + kd * C2m); // pnmadd: one RN32
    const double rd = (double)r;
    const float  p  = (float)(1.0 + (rd + 0.5 * rd * rd));  // RN32(1+r+..)
    e2t[t] = (float)ldexp((double)p, k);      // exact pow2 scale
  }

  const float s    = scale[0];
  const float rs   = __fdiv_rn(1.0f, s);                        // 20.0f
  const float x0i  = floorf(__fmul_rn(-0.6931f, rs));           // -14
  const float bint = floorf(__fmul_rn((float)(0.96963238 / 0.35815147), rs));
  const float ss   = __fmul_rn(s, s);
  const float rss  = __fdiv_rn(1.0f, ss);
  const float cint = floorf(__fmul_rn((float)(1.0 / 0.35815147), rss));
  const float lo   = __fmul_rn(30.0f, x0i);                     // -420
  const float rx0  = __fdiv_rn(1.0f, x0i);                      // RN(-1/14)

  // ---- load both rows (4 independent float4 streams), arcp scale ----
  float a[2][8];
#pragma unroll
  for (int k = 0; k < 2; k++) {
    const float* p = x + base0 + (long long)k * ROWLEN + 8 * t;
    float4 va = *(const float4*)(p);
    float4 vb = *(const float4*)(p + 4);
    a[k][0] = __fmul_rn(va.x, rs); a[k][1] = __fmul_rn(va.y, rs);
    a[k][2] = __fmul_rn(va.z, rs); a[k][3] = __fmul_rn(va.w, rs);
    a[k][4] = __fmul_rn(vb.x, rs); a[k][5] = __fmul_rn(vb.y, rs);
    a[k][6] = __fmul_rn(vb.z, rs); a[k][7] = __fmul_rn(vb.w, rs);
  }

  // ---- row max per row: r15 replay ----
  float mk[2];
#pragma unroll
  for (int k = 0; k < 2; k++) {
    float m = a[k][0];
#pragma unroll
    for (int j = 1; j < 8; j++) m = fmaxf(m, a[k][j]);
#pragma unroll
    for (int o = 32; o > 0; o >>= 1) m = fmaxf(m, __shfl_xor(m, o, 64));
    mk[k] = m;
  }
  if ((t & 63) == 0) {
    smax[0][wave] = mk[0];
    smax[1][wave] = mk[1];
  }
  __syncthreads();  // barrier 1: smax + e2t
#pragma unroll
  for (int k = 0; k < 2; k++)
    mk[k] = fmaxf(fmaxf(smax[k][0], smax[k][1]),
                  fmaxf(smax[k][2], smax[k][3]));

  // ---- exp_int (r15 chain verbatim) + r15 esum fold/butterfly ----
  float pe[2];
#pragma unroll
  for (int k = 0; k < 2; k++) {
    pe[k] = 0.0f;
#pragma unroll
    for (int j = 0; j < 8; j++) {
      float xi = __fsub_rn(a[k][j], mk[k]);           // 0 at argmax
      xi = fmaxf(xi, lo);
      float qf = floorf(__fmul_rn(xi, rx0));          // 0..30
      float r  = __fsub_rn(xi, __fmul_rn(x0i, qf));   // no FMA
      float z  = __fadd_rn(__fmul_rn(r, __fadd_rn(r, bint)), cint);
      int   qi = (int)qf;
      float e  = floorf(__fmul_rn(z, e2t[45 - qi]));  // cephes exp2(30-q)
      e = fmaxf(e, 0.0f);
      a[k][j] = e;                                    // ei in place
      pe[k] = __fadd_rn(pe[k], e);                    // r15 thread fold
    }
#pragma unroll
    for (int o = 32; o > 0; o >>= 1)
      pe[k] = __fadd_rn(pe[k], __shfl_xor(pe[k], o, 64));
  }
  if ((t & 63) == 0) {
    ssum[0][wave] = pe[0];
    ssum[1][wave] = pe[1];
  }
  __syncthreads();  // barrier 2: ssum
  float esum[2];
#pragma unroll
  for (int k = 0; k < 2; k++)
    esum[k] = __fadd_rn(__fadd_rn(ssum[k][0], ssum[k][1]),
                        __fadd_rn(ssum[k][2], ssum[k][3]));

  // ---- qlog + deq (r15 verbatim) + r15 dsum ----
  float pd[2];
#pragma unroll
  for (int k = 0; k < 2; k++) {
    pd[k] = 0.0f;
#pragma unroll
    for (int j = 0; j < 8; j++) {
      float R = __fdiv_rn(esum[k], a[k][j]);  // true elementwise divide
      float v = rintf(R);                     // half-to-even
      unsigned ui = __float_as_uint(v);
      int big = (int)(ui >> 23) - 127;        // v >= 1
      if (big > 46) big = 46;
      int bump = (__fsub_rn(v, e2t[big + 15]) >= e2t[big + 14]) ? 1 : 0;
      int q = big + bump;
      if (q > 15) q = 15;
      float d = e2t[15 - q];                  // cephes exp2(-q)
      a[k][j] = d;                            // dq in place
      pd[k] += d;                             // r15 plain-add fold
    }
#pragma unroll
    for (int o = 32; o > 0; o >>= 1)
      pd[k] += __shfl_xor(pd[k], o, 64);
  }
  if ((t & 63) == 0) {
    sdq[0][wave] = pd[0];
    sdq[1][wave] = pd[1];
  }
  __syncthreads();  // barrier 3: sdq
#pragma unroll
  for (int k = 0; k < 2; k++) {
    const float dsum = (sdq[k][0] + sdq[k][1]) + (sdq[k][2] + sdq[k][3]);
    const float dinv = __fdiv_rn(1.0f, dsum);  // arcp: deq * RN(1/dsum)
    f32x4 w0, w1;
    w0.x = __fmul_rn(a[k][0], dinv); w0.y = __fmul_rn(a[k][1], dinv);
    w0.z = __fmul_rn(a[k][2], dinv); w0.w = __fmul_rn(a[k][3], dinv);
    w1.x = __fmul_rn(a[k][4], dinv); w1.y = __fmul_rn(a[k][5], dinv);
    w1.z = __fmul_rn(a[k][6], dinv); w1.w = __fmul_rn(a[k][7], dinv);
    float* p = out + base0 + (long long)k * ROWLEN + 8 * t;
    __builtin_nontemporal_store(w0, (f32x4*)(p));
    __builtin_nontemporal_store(w1, (f32x4*)(p + 4));
  }
}

extern "C" void kernel_launch(void* const* d_in, const int* in_sizes, int n_in,
                              void* d_out, int out_size, void* d_ws, size_t ws_size,
                              hipStream_t stream) {
  const float* x = (const float*)d_in[0];
  const float* scale = (const float*)d_in[1];
  float* out = (float*)d_out;
  const int rows = out_size / ROWLEN;  // 32768
  qis_kernel<<<dim3(rows / 2), dim3(NTHREADS), 0, stream>>>(x, scale, out);
}